// Round 6
// baseline (173.617 us; speedup 1.0000x reference)
//
#include <hip/hip_runtime.h>
#include <hip/hip_bf16.h>
#include <math.h>

#define NBINS 10
#define NVALS 21   // 0:bce, 1..10: C_k (cumulative counts), 11..20: S_k (cumulative sums)
#define THREADS 256

// Per-element: pure-register cumulative accumulation (no LDS, no ballots).
//   C_k += 1[bin >= k],  S_k += (bin >= k) ? (p-t) : 0
// One v_cmp per k is shared by both accumulators.
__device__ __forceinline__ void proc(float x0, float t0, float& bce_acc,
                                     unsigned* __restrict__ ck,
                                     float* __restrict__ sk) {
  bool valid = (x0 == x0) && (t0 == t0);          // single v_cmp_o
  float x = x0;
  float t = __builtin_amdgcn_fmed3f(t0, 0.f, 1.f);

  // sigmoid pieces; softplus(-x) = -ln(sigmoid(x))
  float e = __expf(-fabsf(x));                    // v_mul + v_exp
  float L = 1.f + e;
  float r = __builtin_amdgcn_rcpf(L);
  float p = (x >= 0.f) ? r : e * r;               // sigmoid(x)
  float l2p = __log2f(p);                         // log2(sigmoid)
  const float NLN2 = -0.6931471805599453f;
  float coef2 = __builtin_fmaf(79.f * NLN2, t, NLN2);  // -(80t+1-t)*ln2
  float omtx = __builtin_fmaf(-t, x, x);               // (1-t)*x
  float b = __builtin_fmaf(coef2, l2p, omtx);          // bce (NaN if invalid; masked)
  bce_acc += valid ? b : 0.f;

  int ib = (int)(p * 10.f);
  ib = ib > 9 ? 9 : ib;
  int bin = valid ? ib : -1;                      // invalid excluded from all k
  float dv = p - t;                               // masked by bin<0 below

#pragma unroll
  for (int k = 0; k < NBINS; ++k) {
    bool ge = bin >= k;                           // one v_cmp, shared
    ck[k] += ge ? 1u : 0u;                        // v_addc path
    sk[k] += ge ? dv : 0.f;                       // v_cndmask + v_add
  }
}

__global__ __launch_bounds__(THREADS, 8) void dl_partial(
    const float* __restrict__ pred, const float* __restrict__ targ,
    long long n, float* __restrict__ ws, int grid) {
  __shared__ float red[4][NVALS];

  const int tid = threadIdx.x;
  const long long gid = (long long)blockIdx.x * THREADS + tid;
  const long long stride = (long long)grid * THREADS;
  const long long nvec = n >> 2;

  float bce_acc = 0.f;
  unsigned ck[NBINS];
  float sk[NBINS];
#pragma unroll
  for (int b = 0; b < NBINS; ++b) { ck[b] = 0u; sk[b] = 0.f; }

  const float4* p4 = (const float4*)pred;
  const float4* t4 = (const float4*)targ;
  for (long long i = gid; i < nvec; i += stride) {
    float4 xv = p4[i];
    float4 tv = t4[i];
    proc(xv.x, tv.x, bce_acc, ck, sk);
    proc(xv.y, tv.y, bce_acc, ck, sk);
    proc(xv.z, tv.z, bce_acc, ck, sk);
    proc(xv.w, tv.w, bce_acc, ck, sk);
  }
  long long ti = (nvec << 2) + gid;
  if (ti < n) proc(pred[ti], targ[ti], bce_acc, ck, sk);

  // pack + wave reduce
  float vals[NVALS];
  vals[0] = bce_acc;
#pragma unroll
  for (int b = 0; b < NBINS; ++b) {
    vals[1 + b] = (float)ck[b];    // exact: per-thread count <= 2^24
    vals[11 + b] = sk[b];
  }
#pragma unroll
  for (int v = 0; v < NVALS; ++v) {
#pragma unroll
    for (int off = 32; off; off >>= 1) vals[v] += __shfl_xor(vals[v], off, 64);
  }
  const int lane = tid & 63;
  const int wave = tid >> 6;
  if (lane == 0) {
#pragma unroll
    for (int v = 0; v < NVALS; ++v) red[wave][v] = vals[v];
  }
  __syncthreads();
  if (tid < NVALS) {
    float s = red[0][tid] + red[1][tid] + red[2][tid] + red[3][tid];
    ws[(long long)tid * grid + blockIdx.x] = s;  // SoA for coalesced final pass
  }
}

__global__ __launch_bounds__(THREADS) void dl_final(
    const float* __restrict__ ws, float* __restrict__ out, int grid) {
  __shared__ double totals[NVALS];
  __shared__ double wred[4];
  const int tid = threadIdx.x;
  for (int r = 0; r < NVALS; ++r) {
    double psum = 0.0;
    for (int i = tid; i < grid; i += THREADS)
      psum += (double)ws[(long long)r * grid + i];
#pragma unroll
    for (int off = 32; off; off >>= 1) psum += __shfl_xor(psum, off, 64);
    if ((tid & 63) == 0) wred[tid >> 6] = psum;
    __syncthreads();
    if (tid == 0) totals[r] = wred[0] + wred[1] + wred[2] + wred[3];
    __syncthreads();
  }
  if (tid == 0) {
    double bce = totals[0];
    double nv = totals[1];  // C_0 = n_valid
    double dist = 0.0;
    for (int b = 0; b < NBINS; ++b) {
      double Cb = totals[1 + b];
      double Cb1 = (b < NBINS - 1) ? totals[2 + b] : 0.0;
      double Sb = totals[11 + b];
      double Sb1 = (b < NBINS - 1) ? totals[12 + b] : 0.0;
      double c = Cb - Cb1;          // per-bin count (exact)
      double sd = Sb - Sb1;         // per-bin sum (p-t)
      double safe = c > 1.0 ? c : 1.0;
      if (c > 10.0) dist += fabs(sd) / safe;
    }
    out[0] = (float)(bce / nv + dist / (double)NBINS * 0.2);
  }
}

extern "C" void kernel_launch(void* const* d_in, const int* in_sizes, int n_in,
                              void* d_out, int out_size, void* d_ws, size_t ws_size,
                              hipStream_t stream) {
  const float* pred = (const float*)d_in[0];
  const float* targ = (const float*)d_in[1];
  const long long n = (long long)in_sizes[0];
  float* out = (float*)d_out;
  float* ws = (float*)d_ws;

  int grid = 2048;  // 8 blocks/CU x 256 CUs; no big LDS -> 100% occupancy target
  while (grid > 64 && (size_t)NVALS * grid * sizeof(float) > ws_size) grid >>= 1;

  dl_partial<<<grid, THREADS, 0, stream>>>(pred, targ, n, ws, grid);
  dl_final<<<1, THREADS, 0, stream>>>(ws, out, grid);
}